// Round 1
// baseline (1269.024 us; speedup 1.0000x reference)
//
#include <hip/hip_runtime.h>

typedef short bf16x8 __attribute__((ext_vector_type(8)));
typedef float f32x4 __attribute__((ext_vector_type(4)));
typedef unsigned short u16;
typedef unsigned int u32;

#define TOKS 8192
#define DDIM 1024
#define HDIM 2048
#define NEXP 8
#define ROWS_TOTAL (2 * TOKS)

__device__ __forceinline__ u16 f2b(float f) {
  u32 x;
  __builtin_memcpy(&x, &f, 4);
  return (u16)((x + 0x7fffu + ((x >> 16) & 1u)) >> 16);  // RNE
}

// async global->LDS, 16B per lane. LDS side: wave-uniform base + lane*16.
typedef const __attribute__((address_space(1))) u32* gp_t;
typedef __attribute__((address_space(3))) u32* lp_t;
__device__ __forceinline__ void glds16(const void* g, void* l) {
  __builtin_amdgcn_global_load_lds((gp_t)g, (lp_t)l, 16, 0, 0);
}

// ---------------- x fp32 -> bf16 (layout kept) ----------------
__global__ __launch_bounds__(256) void cvt_x_kernel(const float* __restrict__ in,
                                                    u16* __restrict__ out) {
  size_t i = ((size_t)blockIdx.x * 256 + threadIdx.x) * 8;
  float4 a = *(const float4*)(in + i);
  float4 b = *(const float4*)(in + i + 4);
  union { int4 v; u16 u[8]; } o;
  o.u[0] = f2b(a.x); o.u[1] = f2b(a.y); o.u[2] = f2b(a.z); o.u[3] = f2b(a.w);
  o.u[4] = f2b(b.x); o.u[5] = f2b(b.y); o.u[6] = f2b(b.z); o.u[7] = f2b(b.w);
  *(int4*)(out + i) = o.v;
}

// ---------------- weight [K][N] fp32 -> [N][K] bf16 (64x64 LDS transpose) ----------------
__global__ __launch_bounds__(256) void cvt_wT_kernel(const float* __restrict__ in,
                                                     u16* __restrict__ out, int K, int N) {
  size_t eo = (size_t)blockIdx.z * K * N;
  in += eo; out += eo;
  int n0 = blockIdx.x * 64, k0 = blockIdx.y * 64;
  __shared__ u16 s[64][72];
  int tid = threadIdx.x;
  int kr = tid >> 4, nc = (tid & 15) * 4;
#pragma unroll
  for (int i = 0; i < 4; ++i) {
    int k = k0 + i * 16 + kr;
    float4 v = *(const float4*)(in + (size_t)k * N + n0 + nc);
    ushort4 u;
    u.x = f2b(v.x); u.y = f2b(v.y); u.z = f2b(v.z); u.w = f2b(v.w);
    *(ushort4*)&s[i * 16 + kr][nc] = u;
  }
  __syncthreads();
  int nl = tid >> 2, kc = tid & 3;
  union { int4 v[2]; u16 u[16]; } o;
#pragma unroll
  for (int j = 0; j < 16; ++j) o.u[j] = s[kc * 16 + j][nl];
  u16* op = out + (size_t)(n0 + nl) * K + k0 + kc * 16;
  *(int4*)op = o.v[0];
  *(int4*)(op + 8) = o.v[1];
}

// ---------------- Router: one wave per token (fp32 in) ----------------
__global__ __launch_bounds__(256) void router_kernel(
    const float* __restrict__ x, const float* __restrict__ Wg,
    const float* __restrict__ bg, int* __restrict__ counts,
    int* __restrict__ tok_ids, float* __restrict__ gates) {
  int lane = threadIdx.x & 63;
  int t = blockIdx.x * 4 + (threadIdx.x >> 6);
  const float* xr = x + (size_t)t * DDIM;
  float acc[NEXP];
#pragma unroll
  for (int e = 0; e < NEXP; ++e) acc[e] = 0.f;
#pragma unroll
  for (int jj = 0; jj < DDIM / 64; ++jj) {
    int d = jj * 64 + lane;
    float xv = xr[d];
    float4 w0 = *(const float4*)(Wg + d * NEXP);
    float4 w1v = *(const float4*)(Wg + d * NEXP + 4);
    acc[0] += xv * w0.x; acc[1] += xv * w0.y; acc[2] += xv * w0.z; acc[3] += xv * w0.w;
    acc[4] += xv * w1v.x; acc[5] += xv * w1v.y; acc[6] += xv * w1v.z; acc[7] += xv * w1v.w;
  }
#pragma unroll
  for (int off = 32; off > 0; off >>= 1) {
#pragma unroll
    for (int e = 0; e < NEXP; ++e) acc[e] += __shfl_down(acc[e], off, 64);
  }
  if (lane == 0) {
    float v[NEXP];
#pragma unroll
    for (int e = 0; e < NEXP; ++e) v[e] = acc[e] + bg[e];
    int e0 = 0;
    float v0 = v[0];
#pragma unroll
    for (int e = 1; e < NEXP; ++e)
      if (v[e] > v0) { v0 = v[e]; e0 = e; }  // strict >: lowest index wins ties (jax)
    int e1 = -1;
    float v1 = -3.4e38f;
#pragma unroll
    for (int e = 0; e < NEXP; ++e)
      if (e != e0 && v[e] > v1) { v1 = v[e]; e1 = e; }
    if (e1 < 0) e1 = (e0 + 1) & 7;  // NaN hard-guard
    float ex = __expf(v1 - v0);
    float g0 = 1.f / (1.f + ex);
    float g1 = 1.f - g0;
    int s0 = atomicAdd(&counts[e0], 1);
    if (s0 < TOKS) { tok_ids[e0 * TOKS + s0] = t; gates[e0 * TOKS + s0] = g0; }
    int s1 = atomicAdd(&counts[e1], 1);
    if (s1 < TOKS) { tok_ids[e1 * TOKS + s1] = t; gates[e1 * TOKS + s1] = g1; }
  }
}

__global__ void offsets_kernel(const int* __restrict__ counts, int* __restrict__ offsets) {
  if (threadIdx.x == 0) {
    int o = 0;
    for (int e = 0; e < NEXP; ++e) { offsets[e] = o; o += counts[e]; }
  }
}

// ---------------- Stage A: h = silu(xb@w1t^T)*(xb@w3t^T) ----------------
// w1t/w3t: [N=HDIM][K=DDIM] bf16. LDS rows packed 64B + XOR swizzle on global chunk.
// Pipelined: double-buffered LDS, next-tile global_load_lds issued before current-tile
// compute, raw s_barrier + counted s_waitcnt vmcnt(6) so prefetch stays in flight
// across the barrier (no compiler vmcnt(0) drain per K-step).
__global__ __launch_bounds__(256) void ffn1_kernel(
    const u16* __restrict__ xb, const u16* __restrict__ w1t,
    const u16* __restrict__ w3t, const int* __restrict__ tok_ids,
    const int* __restrict__ counts, const int* __restrict__ offsets,
    u16* __restrict__ h, int nbase, int hw, int e_arg) {
  int e = (e_arg >= 0) ? e_arg : (int)blockIdx.z;
  int count = counts[e];
  int mbase = blockIdx.x * 128;
  if (mbase >= count) return;
  int row_off = (e_arg >= 0) ? 0 : offsets[e];
  int n0g = nbase + blockIdx.y * 128;
  size_t we = (e_arg >= 0) ? 0 : (size_t)e;
  const u16* w1e = w1t + we * (size_t)(HDIM * DDIM);
  const u16* w3e = w3t + we * (size_t)(HDIM * DDIM);

  // 2 buffers x 24 segments x 512 u16 = 48 KiB. seg 0-7: A, 8-15: B1, 16-23: B3.
  __shared__ u16 sbuf[2][24 * 512];
  __shared__ int stok[128];

  int tid = threadIdx.x, lane = tid & 63, wv = tid >> 6;
  if (tid < 128) {
    int s = mbase + tid;
    if (s >= count) s = count - 1;
    stok[tid] = tok_ids[e * TOKS + s];
  }
  __syncthreads();

  // per-wave staging: 24 segments of 1KB (16 rows x 64B); 6 per wave
  int rloc = lane >> 2, ch = lane & 3;
  const u16* gsrc[6];
  int soff[6];
#pragma unroll
  for (int i = 0; i < 6; ++i) {
    int s = wv * 6 + i;
    soff[i] = s * 512;
    if (s < 8) {
      int r = s * 16 + rloc;
      int sw = ch ^ ((r >> 1) & 3);
      gsrc[i] = xb + (size_t)stok[r] * DDIM + sw * 8;
    } else if (s < 16) {
      int r = (s - 8) * 16 + rloc;
      int sw = ch ^ ((r >> 1) & 3);
      gsrc[i] = w1e + (size_t)(n0g + r) * DDIM + sw * 8;
    } else {
      int r = (s - 16) * 16 + rloc;
      int sw = ch ^ ((r >> 1) & 3);
      gsrc[i] = w3e + (size_t)(n0g + r) * DDIM + sw * 8;
    }
  }

  int wm = wv >> 1, wn = wv & 1;
  int rsel = lane & 15, q = lane >> 4;

  f32x4 acc1[4][4], acc3[4][4];
#pragma unroll
  for (int i = 0; i < 4; ++i)
#pragma unroll
    for (int j = 0; j < 4; ++j) {
      f32x4 z = {0.f, 0.f, 0.f, 0.f};
      acc1[i][j] = z; acc3[i][j] = z;
    }

  // prologue: stage k0=0 into buffer 0
#pragma unroll
  for (int i = 0; i < 6; ++i) glds16(gsrc[i], &sbuf[0][soff[i]]);

  int buf = 0;
  const int NIT = DDIM / 32;
  for (int it = 0; it < NIT; ++it) {
    if (it + 1 < NIT) {
      int kn = (it + 1) * 32;
#pragma unroll
      for (int i = 0; i < 6; ++i) glds16(gsrc[i] + kn, &sbuf[buf ^ 1][soff[i]]);
      asm volatile("s_waitcnt vmcnt(6)" ::: "memory");  // my current-buffer loads done
    } else {
      asm volatile("s_waitcnt vmcnt(0)" ::: "memory");
    }
    __builtin_amdgcn_s_barrier();  // everyone's current-buffer loads done

    const u16* sA  = &sbuf[buf][0];
    const u16* sB1 = &sbuf[buf][8 * 512];
    const u16* sB3 = &sbuf[buf][16 * 512];

    bf16x8 aF[4], b1F[4], b3F[4];
#pragma unroll
    for (int mi = 0; mi < 4; ++mi) {
      int r = wm * 64 + mi * 16 + rsel;
      int p = q ^ ((r >> 1) & 3);
      aF[mi] = *(const bf16x8*)&sA[r * 32 + p * 8];
    }
#pragma unroll
    for (int ni = 0; ni < 4; ++ni) {
      int r = wn * 64 + ni * 16 + rsel;
      int p = q ^ ((r >> 1) & 3);
      b1F[ni] = *(const bf16x8*)&sB1[r * 32 + p * 8];
      b3F[ni] = *(const bf16x8*)&sB3[r * 32 + p * 8];
    }
    asm volatile("s_waitcnt lgkmcnt(0)" ::: "memory");  // my LDS reads landed
    __builtin_amdgcn_s_barrier();  // all reads done -> next iter may restage this buf

#pragma unroll
    for (int mi = 0; mi < 4; ++mi)
#pragma unroll
      for (int ni = 0; ni < 4; ++ni) {
        acc1[mi][ni] = __builtin_amdgcn_mfma_f32_16x16x32_bf16(aF[mi], b1F[ni], acc1[mi][ni], 0, 0, 0);
        acc3[mi][ni] = __builtin_amdgcn_mfma_f32_16x16x32_bf16(aF[mi], b3F[ni], acc3[mi][ni], 0, 0, 0);
      }
    buf ^= 1;
  }

  int cm = count - mbase;
#pragma unroll
  for (int mi = 0; mi < 4; ++mi) {
#pragma unroll
    for (int rr = 0; rr < 4; ++rr) {
      int m = wm * 64 + mi * 16 + q * 4 + rr;  // C/D: row = quad*4+reg
      if (m < cm) {
#pragma unroll
        for (int ni = 0; ni < 4; ++ni) {
          int nl = blockIdx.y * 128 + wn * 64 + ni * 16 + rsel;  // local col in chunk
          float u = acc1[mi][ni][rr];
          float vv = acc3[mi][ni][rr];
          float hv = (u / (1.f + __expf(-u))) * vv;  // silu(u)*v
          h[(size_t)(row_off + mbase + m) * hw + nl] = f2b(hv);
        }
      }
    }
  }
}

// ---------------- Stage B: out[tok] += gate * (h @ w2t^T) ----------------
// w2t: [N=DDIM][K=HDIM] bf16. Same pipelined double-buffer structure, vmcnt(4).
__global__ __launch_bounds__(256) void ffn2_kernel(
    const u16* __restrict__ h, const u16* __restrict__ w2t,
    const int* __restrict__ tok_ids, const float* __restrict__ gates,
    const int* __restrict__ counts, const int* __restrict__ offsets,
    float* __restrict__ out, int kbase, int hw, int e_arg) {
  int e = (e_arg >= 0) ? e_arg : (int)blockIdx.z;
  int count = counts[e];
  int mbase = blockIdx.x * 128;
  if (mbase >= count) return;
  int row_off = (e_arg >= 0) ? 0 : offsets[e];
  int n0 = blockIdx.y * 128;
  size_t we = (e_arg >= 0) ? 0 : (size_t)e;
  const u16* w2e = w2t + we * (size_t)(HDIM * DDIM);

  // 2 buffers x 16 segments x 512 u16 = 32 KiB. seg 0-7: A(h), 8-15: B(w2).
  __shared__ u16 sbuf[2][16 * 512];
  __shared__ int stok[128];
  __shared__ float sg[128];

  int tid = threadIdx.x, lane = tid & 63, wv = tid >> 6;
  if (tid < 128) {
    int s = mbase + tid;
    if (s >= count) s = count - 1;
    stok[tid] = tok_ids[e * TOKS + s];
    sg[tid] = gates[e * TOKS + s];
  }
  __syncthreads();

  int rloc = lane >> 2, ch = lane & 3;
  const u16* gsrc[4];
  int soff[4];
#pragma unroll
  for (int i = 0; i < 4; ++i) {
    int s = wv * 4 + i;
    soff[i] = s * 512;
    if (s < 8) {
      int r = s * 16 + rloc;
      int slot = mbase + r;
      if (slot >= count) slot = count - 1;
      int sw = ch ^ ((r >> 1) & 3);
      gsrc[i] = h + (size_t)(row_off + slot) * hw + sw * 8;
    } else {
      int r = (s - 8) * 16 + rloc;
      int sw = ch ^ ((r >> 1) & 3);
      gsrc[i] = w2e + (size_t)(n0 + r) * HDIM + kbase + sw * 8;
    }
  }

  int wm = wv >> 1, wn = wv & 1;
  int rsel = lane & 15, q = lane >> 4;

  f32x4 acc[4][4];
#pragma unroll
  for (int i = 0; i < 4; ++i)
#pragma unroll
    for (int j = 0; j < 4; ++j) {
      f32x4 z = {0.f, 0.f, 0.f, 0.f};
      acc[i][j] = z;
    }

  // prologue: stage k0=0 into buffer 0
#pragma unroll
  for (int i = 0; i < 4; ++i) glds16(gsrc[i], &sbuf[0][soff[i]]);

  int buf = 0;
  for (int k0 = 0; k0 < hw; k0 += 32) {
    if (k0 + 32 < hw) {
      int kn = k0 + 32;
#pragma unroll
      for (int i = 0; i < 4; ++i) glds16(gsrc[i] + kn, &sbuf[buf ^ 1][soff[i]]);
      asm volatile("s_waitcnt vmcnt(4)" ::: "memory");
    } else {
      asm volatile("s_waitcnt vmcnt(0)" ::: "memory");
    }
    __builtin_amdgcn_s_barrier();

    const u16* sA = &sbuf[buf][0];
    const u16* sB = &sbuf[buf][8 * 512];

    bf16x8 aF[4], bF[4];
#pragma unroll
    for (int mi = 0; mi < 4; ++mi) {
      int r = wm * 64 + mi * 16 + rsel;
      int p = q ^ ((r >> 1) & 3);
      aF[mi] = *(const bf16x8*)&sA[r * 32 + p * 8];
    }
#pragma unroll
    for (int ni = 0; ni < 4; ++ni) {
      int r = wn * 64 + ni * 16 + rsel;
      int p = q ^ ((r >> 1) & 3);
      bF[ni] = *(const bf16x8*)&sB[r * 32 + p * 8];
    }
    asm volatile("s_waitcnt lgkmcnt(0)" ::: "memory");
    __builtin_amdgcn_s_barrier();

#pragma unroll
    for (int mi = 0; mi < 4; ++mi)
#pragma unroll
      for (int ni = 0; ni < 4; ++ni)
        acc[mi][ni] = __builtin_amdgcn_mfma_f32_16x16x32_bf16(aF[mi], bF[ni], acc[mi][ni], 0, 0, 0);
    buf ^= 1;
  }

  int cm = count - mbase;
#pragma unroll
  for (int mi = 0; mi < 4; ++mi) {
#pragma unroll
    for (int rr = 0; rr < 4; ++rr) {
      int m = wm * 64 + mi * 16 + q * 4 + rr;
      if (m < cm) {
        int t = stok[m];
        float g = sg[m];
#pragma unroll
        for (int ni = 0; ni < 4; ++ni) {
          int col = n0 + wn * 64 + ni * 16 + rsel;
          atomicAdd(&out[(size_t)t * DDIM + col], g * acc[mi][ni][rr]);
        }
      }
    }
  }
}

extern "C" void kernel_launch(void* const* d_in, const int* in_sizes, int n_in,
                              void* d_out, int out_size, void* d_ws, size_t ws_size,
                              hipStream_t stream) {
  (void)in_sizes; (void)n_in; (void)out_size;
  const float* x  = (const float*)d_in[0];
  const float* Wg = (const float*)d_in[1];
  const float* bg = (const float*)d_in[2];
  const float* w1 = (const float*)d_in[3];
  const float* w3 = (const float*)d_in[4];
  const float* w2 = (const float*)d_in[5];
  float* out = (float*)d_out;

  char* ws = (char*)d_ws;
  int*   tok_ids = (int*)ws;               // 262144 B
  float* gates   = (float*)(ws + 262144);  // 262144 B
  int*   counts  = (int*)(ws + 524288);
  int*   offsets = (int*)(ws + 524352);
  u16*   xb      = (u16*)(ws + (1 << 20)); // 16.78 MB

  const size_t WEXP  = (size_t)HDIM * DDIM * 2;          // 4 MiB per weight per expert
  const size_t WALL  = 3ull * NEXP * WEXP;               // 100.7 MB
  const size_t HFULL = (size_t)ROWS_TOTAL * HDIM * 2;    // 67.1 MB
  const size_t base  = (1 << 20) + 16777216ull;

  hipMemsetAsync(counts, 0, 128, stream);
  hipMemsetAsync(out, 0, (size_t)TOKS * DDIM * 4, stream);

  cvt_x_kernel<<<TOKS * DDIM / (256 * 8), 256, 0, stream>>>(x, xb);
  router_kernel<<<TOKS / 4, 256, 0, stream>>>(x, Wg, bg, counts, tok_ids, gates);
  offsets_kernel<<<1, 64, 0, stream>>>(counts, offsets);

  if (ws_size >= base + WALL + HFULL) {
    // Mode A: all weights converted once, single big ffn launches across experts
    u16* w1t = (u16*)(ws + base);
    u16* w3t = w1t + (size_t)NEXP * HDIM * DDIM;
    u16* w2t = w3t + (size_t)NEXP * HDIM * DDIM;
    u16* hb  = w2t + (size_t)NEXP * HDIM * DDIM;
    cvt_wT_kernel<<<dim3(HDIM / 64, DDIM / 64, NEXP), 256, 0, stream>>>(w1, w1t, DDIM, HDIM);
    cvt_wT_kernel<<<dim3(HDIM / 64, DDIM / 64, NEXP), 256, 0, stream>>>(w3, w3t, DDIM, HDIM);
    cvt_wT_kernel<<<dim3(DDIM / 64, HDIM / 64, NEXP), 256, 0, stream>>>(w2, w2t, HDIM, DDIM);
    ffn1_kernel<<<dim3(64, HDIM / 128, NEXP), 256, 0, stream>>>(
        xb, w1t, w3t, tok_ids, counts, offsets, hb, 0, HDIM, -1);
    ffn2_kernel<<<dim3(64, DDIM / 128, NEXP), 256, 0, stream>>>(
        hb, w2t, tok_ids, gates, counts, offsets, out, 0, HDIM, -1);
  } else {
    // Mode B: per-expert weight buffers + h chunking
    int hw = 128;
    const int cand[5] = {2048, 1024, 512, 256, 128};
    for (int i = 0; i < 5; ++i)
      if (base + 3 * WEXP + (size_t)TOKS * cand[i] * 2 <= ws_size) { hw = cand[i]; break; }
    u16* w1t = (u16*)(ws + base);
    u16* w3t = w1t + (size_t)HDIM * DDIM;
    u16* w2t = w3t + (size_t)HDIM * DDIM;
    u16* hb  = w2t + (size_t)HDIM * DDIM;
    for (int e = 0; e < NEXP; ++e) {
      cvt_wT_kernel<<<dim3(HDIM / 64, DDIM / 64, 1), 256, 0, stream>>>(
          w1 + (size_t)e * DDIM * HDIM, w1t, DDIM, HDIM);
      cvt_wT_kernel<<<dim3(HDIM / 64, DDIM / 64, 1), 256, 0, stream>>>(
          w3 + (size_t)e * DDIM * HDIM, w3t, DDIM, HDIM);
      cvt_wT_kernel<<<dim3(DDIM / 64, HDIM / 64, 1), 256, 0, stream>>>(
          w2 + (size_t)e * HDIM * DDIM, w2t, HDIM, DDIM);
      for (int nbase = 0; nbase < HDIM; nbase += hw) {
        ffn1_kernel<<<dim3(64, hw / 128, 1), 256, 0, stream>>>(
            xb, w1t, w3t, tok_ids, counts, offsets, hb, nbase, hw, e);
        ffn2_kernel<<<dim3(64, DDIM / 128, 1), 256, 0, stream>>>(
            hb, w2t, tok_ids, gates, counts, offsets, out, nbase, hw, e);
      }
    }
  }
}

// Round 2
// 893.020 us; speedup vs baseline: 1.4210x; 1.4210x over previous
//
#include <hip/hip_runtime.h>

typedef short bf16x8 __attribute__((ext_vector_type(8)));
typedef float f32x4 __attribute__((ext_vector_type(4)));
typedef unsigned short u16;
typedef unsigned int u32;

#define TOKS 8192
#define DDIM 1024
#define HDIM 2048
#define NEXP 8
#define ROWS_TOTAL (2 * TOKS)

__device__ __forceinline__ u16 f2b(float f) {
  u32 x;
  __builtin_memcpy(&x, &f, 4);
  return (u16)((x + 0x7fffu + ((x >> 16) & 1u)) >> 16);  // RNE
}

// async global->LDS, 16B per lane. LDS side: wave-uniform base + lane*16.
typedef const __attribute__((address_space(1))) u32* gp_t;
typedef __attribute__((address_space(3))) u32* lp_t;
__device__ __forceinline__ void glds16(const void* g, void* l) {
  __builtin_amdgcn_global_load_lds((gp_t)g, (lp_t)l, 16, 0, 0);
}

// ---------------- x fp32 -> bf16 (layout kept) ----------------
__global__ __launch_bounds__(256) void cvt_x_kernel(const float* __restrict__ in,
                                                    u16* __restrict__ out) {
  size_t i = ((size_t)blockIdx.x * 256 + threadIdx.x) * 8;
  float4 a = *(const float4*)(in + i);
  float4 b = *(const float4*)(in + i + 4);
  union { int4 v; u16 u[8]; } o;
  o.u[0] = f2b(a.x); o.u[1] = f2b(a.y); o.u[2] = f2b(a.z); o.u[3] = f2b(a.w);
  o.u[4] = f2b(b.x); o.u[5] = f2b(b.y); o.u[6] = f2b(b.z); o.u[7] = f2b(b.w);
  *(int4*)(out + i) = o.v;
}

// ---------------- weight [K][N] fp32 -> [N][K] bf16 (64x64 LDS transpose) ----------------
__global__ __launch_bounds__(256) void cvt_wT_kernel(const float* __restrict__ in,
                                                     u16* __restrict__ out, int K, int N) {
  size_t eo = (size_t)blockIdx.z * K * N;
  in += eo; out += eo;
  int n0 = blockIdx.x * 64, k0 = blockIdx.y * 64;
  __shared__ u16 s[64][72];
  int tid = threadIdx.x;
  int kr = tid >> 4, nc = (tid & 15) * 4;
#pragma unroll
  for (int i = 0; i < 4; ++i) {
    int k = k0 + i * 16 + kr;
    float4 v = *(const float4*)(in + (size_t)k * N + n0 + nc);
    ushort4 u;
    u.x = f2b(v.x); u.y = f2b(v.y); u.z = f2b(v.z); u.w = f2b(v.w);
    *(ushort4*)&s[i * 16 + kr][nc] = u;
  }
  __syncthreads();
  int nl = tid >> 2, kc = tid & 3;
  union { int4 v[2]; u16 u[16]; } o;
#pragma unroll
  for (int j = 0; j < 16; ++j) o.u[j] = s[kc * 16 + j][nl];
  u16* op = out + (size_t)(n0 + nl) * K + k0 + kc * 16;
  *(int4*)op = o.v[0];
  *(int4*)(op + 8) = o.v[1];
}

// ---------------- Router: one wave per token (fp32 in) ----------------
__global__ __launch_bounds__(256) void router_kernel(
    const float* __restrict__ x, const float* __restrict__ Wg,
    const float* __restrict__ bg, int* __restrict__ counts,
    int* __restrict__ tok_ids, float* __restrict__ gates) {
  int lane = threadIdx.x & 63;
  int t = blockIdx.x * 4 + (threadIdx.x >> 6);
  const float* xr = x + (size_t)t * DDIM;
  float acc[NEXP];
#pragma unroll
  for (int e = 0; e < NEXP; ++e) acc[e] = 0.f;
#pragma unroll
  for (int jj = 0; jj < DDIM / 64; ++jj) {
    int d = jj * 64 + lane;
    float xv = xr[d];
    float4 w0 = *(const float4*)(Wg + d * NEXP);
    float4 w1v = *(const float4*)(Wg + d * NEXP + 4);
    acc[0] += xv * w0.x; acc[1] += xv * w0.y; acc[2] += xv * w0.z; acc[3] += xv * w0.w;
    acc[4] += xv * w1v.x; acc[5] += xv * w1v.y; acc[6] += xv * w1v.z; acc[7] += xv * w1v.w;
  }
#pragma unroll
  for (int off = 32; off > 0; off >>= 1) {
#pragma unroll
    for (int e = 0; e < NEXP; ++e) acc[e] += __shfl_down(acc[e], off, 64);
  }
  if (lane == 0) {
    float v[NEXP];
#pragma unroll
    for (int e = 0; e < NEXP; ++e) v[e] = acc[e] + bg[e];
    int e0 = 0;
    float v0 = v[0];
#pragma unroll
    for (int e = 1; e < NEXP; ++e)
      if (v[e] > v0) { v0 = v[e]; e0 = e; }  // strict >: lowest index wins ties (jax)
    int e1 = -1;
    float v1 = -3.4e38f;
#pragma unroll
    for (int e = 0; e < NEXP; ++e)
      if (e != e0 && v[e] > v1) { v1 = v[e]; e1 = e; }
    if (e1 < 0) e1 = (e0 + 1) & 7;  // NaN hard-guard
    float ex = __expf(v1 - v0);
    float g0 = 1.f / (1.f + ex);
    float g1 = 1.f - g0;
    int s0 = atomicAdd(&counts[e0], 1);
    if (s0 < TOKS) { tok_ids[e0 * TOKS + s0] = t; gates[e0 * TOKS + s0] = g0; }
    int s1 = atomicAdd(&counts[e1], 1);
    if (s1 < TOKS) { tok_ids[e1 * TOKS + s1] = t; gates[e1 * TOKS + s1] = g1; }
  }
}

__global__ void offsets_kernel(const int* __restrict__ counts, int* __restrict__ offsets) {
  if (threadIdx.x == 0) {
    int o = 0;
    for (int e = 0; e < NEXP; ++e) { offsets[e] = o; o += counts[e]; }
  }
}

// ---------------- Stage A: h = silu(xb@w1t^T)*(xb@w3t^T) ----------------
// BK=64: rows staged in 128B chunks (better L3/HBM granule), chunk-XOR swizzle (r&7)
// with pre-swizzled global source + swizzled ds_read (both-sides involution).
// Mode A grid is 1-D XCD-swizzled: each XCD owns a y-pair for ALL experts, so the
// w1/w3 panels stay L2-resident across all m-tiles; (m,y0),(m,y1) adjacent so xb rows
// get an L2 hit on the second y.
__global__ __launch_bounds__(256) void ffn1_kernel(
    const u16* __restrict__ xb, const u16* __restrict__ w1t,
    const u16* __restrict__ w3t, const int* __restrict__ tok_ids,
    const int* __restrict__ counts, const int* __restrict__ offsets,
    u16* __restrict__ h, int nbase, int hw, int e_arg) {
  int e, m, y;
  if (e_arg >= 0) {  // Mode B: plain grid
    e = e_arg; m = blockIdx.x; y = blockIdx.y;
  } else {           // Mode A: 1-D XCD-swizzled decode (bijective)
    int bid = blockIdx.x;
    int xcd = bid & 7, s = bid >> 3;   // s: 0..1023
    e = s >> 7;                        // 0..7
    int t = s & 127;                   // 0..127
    m = t >> 1;                        // 0..63
    y = xcd * 2 + (t & 1);             // 0..15
  }
  int count = counts[e];
  int mbase = m * 128;
  if (mbase >= count) return;
  int row_off = (e_arg >= 0) ? 0 : offsets[e];
  int n0g = nbase + y * 128;
  size_t we = (e_arg >= 0) ? 0 : (size_t)e;
  const u16* w1e = w1t + we * (size_t)(HDIM * DDIM);
  const u16* w3e = w3t + we * (size_t)(HDIM * DDIM);

  __shared__ u16 sA[128 * 64];   // 16 KB each
  __shared__ u16 sB1[128 * 64];
  __shared__ u16 sB3[128 * 64];
  __shared__ int stok[128];

  int tid = threadIdx.x, lane = tid & 63, wv = tid >> 6;
  if (tid < 128) {
    int s = mbase + tid;
    if (s >= count) s = count - 1;
    stok[tid] = tok_ids[e * TOKS + s];
  }
  __syncthreads();

  // staging: 48 segments (16 each of A/B1/B3), segment = 8 rows x 128B.
  // wave wv owns segments wv*4..wv*4+3 of each buffer. lane: row = lane>>3, chunk = lane&7.
  int rloc = lane >> 3, ch = lane & 7;
  u32 offA[4], offB[4];  // element offsets; B1/B3 share rows
#pragma unroll
  for (int i = 0; i < 4; ++i) {
    int r = (wv * 4 + i) * 8 + rloc;     // 0..127
    int sw = ch ^ (r & 7);               // source pre-swizzle
    offA[i] = (u32)stok[r] * DDIM + sw * 8;
    offB[i] = (u32)(n0g + r) * DDIM + sw * 8;
  }

  int wm = wv >> 1, wn = wv & 1;
  int rsel = lane & 15, q = lane >> 4;

  f32x4 acc1[4][4], acc3[4][4];
#pragma unroll
  for (int i = 0; i < 4; ++i)
#pragma unroll
    for (int j = 0; j < 4; ++j) {
      f32x4 z = {0.f, 0.f, 0.f, 0.f};
      acc1[i][j] = z; acc3[i][j] = z;
    }

  for (int k0 = 0; k0 < DDIM; k0 += 64) {
    __syncthreads();  // prior reads done before overwrite
#pragma unroll
    for (int i = 0; i < 4; ++i) {
      int sbase = (wv * 4 + i) * 512;
      glds16(xb  + offA[i] + k0, sA  + sbase);
      glds16(w1e + offB[i] + k0, sB1 + sbase);
      glds16(w3e + offB[i] + k0, sB3 + sbase);
    }
    __syncthreads();  // vmcnt(0) drain: staged data visible

#pragma unroll
    for (int ks = 0; ks < 2; ++ks) {
      bf16x8 aF[4], b1F[4], b3F[4];
#pragma unroll
      for (int mi = 0; mi < 4; ++mi) {
        int r = wm * 64 + mi * 16 + rsel;
        int p = (ks * 4 + q) ^ (r & 7);
        aF[mi] = *(const bf16x8*)&sA[r * 64 + p * 8];
      }
#pragma unroll
      for (int ni = 0; ni < 4; ++ni) {
        int r = wn * 64 + ni * 16 + rsel;
        int p = (ks * 4 + q) ^ (r & 7);
        b1F[ni] = *(const bf16x8*)&sB1[r * 64 + p * 8];
        b3F[ni] = *(const bf16x8*)&sB3[r * 64 + p * 8];
      }
#pragma unroll
      for (int mi = 0; mi < 4; ++mi)
#pragma unroll
        for (int ni = 0; ni < 4; ++ni) {
          acc1[mi][ni] = __builtin_amdgcn_mfma_f32_16x16x32_bf16(aF[mi], b1F[ni], acc1[mi][ni], 0, 0, 0);
          acc3[mi][ni] = __builtin_amdgcn_mfma_f32_16x16x32_bf16(aF[mi], b3F[ni], acc3[mi][ni], 0, 0, 0);
        }
    }
  }

  int cm = count - mbase;
#pragma unroll
  for (int mi = 0; mi < 4; ++mi) {
#pragma unroll
    for (int rr = 0; rr < 4; ++rr) {
      int mrow = wm * 64 + mi * 16 + q * 4 + rr;  // C/D: row = quad*4+reg
      if (mrow < cm) {
#pragma unroll
        for (int ni = 0; ni < 4; ++ni) {
          int nl = y * 128 + wn * 64 + ni * 16 + rsel;  // local col in chunk
          float u = acc1[mi][ni][rr];
          float vv = acc3[mi][ni][rr];
          float hv = (u / (1.f + __expf(-u))) * vv;  // silu(u)*v
          h[(size_t)(row_off + mbase + mrow) * hw + nl] = f2b(hv);
        }
      }
    }
  }
}

// ---------------- Stage B: out[tok] += gate * (h @ w2t^T) ----------------
// w2t: [N=DDIM][K=HDIM] bf16. BK=64, same swizzle. Mode A: y = XCD, so each w2
// panel (e,y) is read once into one XCD's L2 and reused across all m-tiles.
__global__ __launch_bounds__(256) void ffn2_kernel(
    const u16* __restrict__ h, const u16* __restrict__ w2t,
    const int* __restrict__ tok_ids, const float* __restrict__ gates,
    const int* __restrict__ counts, const int* __restrict__ offsets,
    float* __restrict__ out, int kbase, int hw, int e_arg) {
  int e, m, y;
  if (e_arg >= 0) {
    e = e_arg; m = blockIdx.x; y = blockIdx.y;
  } else {
    int bid = blockIdx.x;
    int xcd = bid & 7, s = bid >> 3;   // s: 0..511
    y = xcd;                           // DDIM/128 = 8
    e = s >> 6;                        // 0..7
    m = s & 63;                        // 0..63
  }
  int count = counts[e];
  int mbase = m * 128;
  if (mbase >= count) return;
  int row_off = (e_arg >= 0) ? 0 : offsets[e];
  int n0 = y * 128;
  size_t we = (e_arg >= 0) ? 0 : (size_t)e;
  const u16* w2e = w2t + we * (size_t)(HDIM * DDIM);

  __shared__ u16 sA[128 * 64];
  __shared__ u16 sB[128 * 64];
  __shared__ int stok[128];
  __shared__ float sg[128];

  int tid = threadIdx.x, lane = tid & 63, wv = tid >> 6;
  if (tid < 128) {
    int s = mbase + tid;
    if (s >= count) s = count - 1;
    stok[tid] = tok_ids[e * TOKS + s];
    sg[tid] = gates[e * TOKS + s];
  }
  __syncthreads();

  int rloc = lane >> 3, ch = lane & 7;
  u32 offA[4], offB[4];
#pragma unroll
  for (int i = 0; i < 4; ++i) {
    int r = (wv * 4 + i) * 8 + rloc;
    int sw = ch ^ (r & 7);
    int slot = mbase + r;
    if (slot >= count) slot = count - 1;
    offA[i] = (u32)(row_off + slot) * hw + sw * 8;
    offB[i] = (u32)(n0 + r) * HDIM + kbase + sw * 8;
  }

  int wm = wv >> 1, wn = wv & 1;
  int rsel = lane & 15, q = lane >> 4;

  f32x4 acc[4][4];
#pragma unroll
  for (int i = 0; i < 4; ++i)
#pragma unroll
    for (int j = 0; j < 4; ++j) {
      f32x4 z = {0.f, 0.f, 0.f, 0.f};
      acc[i][j] = z;
    }

  for (int k0 = 0; k0 < hw; k0 += 64) {
    __syncthreads();
#pragma unroll
    for (int i = 0; i < 4; ++i) {
      int sbase = (wv * 4 + i) * 512;
      glds16(h   + offA[i] + k0, sA + sbase);
      glds16(w2e + offB[i] + k0, sB + sbase);
    }
    __syncthreads();

#pragma unroll
    for (int ks = 0; ks < 2; ++ks) {
      bf16x8 aF[4], bF[4];
#pragma unroll
      for (int mi = 0; mi < 4; ++mi) {
        int r = wm * 64 + mi * 16 + rsel;
        int p = (ks * 4 + q) ^ (r & 7);
        aF[mi] = *(const bf16x8*)&sA[r * 64 + p * 8];
      }
#pragma unroll
      for (int ni = 0; ni < 4; ++ni) {
        int r = wn * 64 + ni * 16 + rsel;
        int p = (ks * 4 + q) ^ (r & 7);
        bF[ni] = *(const bf16x8*)&sB[r * 64 + p * 8];
      }
#pragma unroll
      for (int mi = 0; mi < 4; ++mi)
#pragma unroll
        for (int ni = 0; ni < 4; ++ni)
          acc[mi][ni] = __builtin_amdgcn_mfma_f32_16x16x32_bf16(aF[mi], bF[ni], acc[mi][ni], 0, 0, 0);
    }
  }

  int cm = count - mbase;
#pragma unroll
  for (int mi = 0; mi < 4; ++mi) {
#pragma unroll
    for (int rr = 0; rr < 4; ++rr) {
      int mrow = wm * 64 + mi * 16 + q * 4 + rr;
      if (mrow < cm) {
        int t = stok[mrow];
        float g = sg[mrow];
#pragma unroll
        for (int ni = 0; ni < 4; ++ni) {
          int col = n0 + wn * 64 + ni * 16 + rsel;
          atomicAdd(&out[(size_t)t * DDIM + col], g * acc[mi][ni][rr]);
        }
      }
    }
  }
}

extern "C" void kernel_launch(void* const* d_in, const int* in_sizes, int n_in,
                              void* d_out, int out_size, void* d_ws, size_t ws_size,
                              hipStream_t stream) {
  (void)in_sizes; (void)n_in; (void)out_size;
  const float* x  = (const float*)d_in[0];
  const float* Wg = (const float*)d_in[1];
  const float* bg = (const float*)d_in[2];
  const float* w1 = (const float*)d_in[3];
  const float* w3 = (const float*)d_in[4];
  const float* w2 = (const float*)d_in[5];
  float* out = (float*)d_out;

  char* ws = (char*)d_ws;
  int*   tok_ids = (int*)ws;               // 262144 B
  float* gates   = (float*)(ws + 262144);  // 262144 B
  int*   counts  = (int*)(ws + 524288);
  int*   offsets = (int*)(ws + 524352);
  u16*   xb      = (u16*)(ws + (1 << 20)); // 16.78 MB

  const size_t WEXP  = (size_t)HDIM * DDIM * 2;          // 4 MiB per weight per expert
  const size_t WALL  = 3ull * NEXP * WEXP;               // 100.7 MB
  const size_t HFULL = (size_t)ROWS_TOTAL * HDIM * 2;    // 67.1 MB
  const size_t base  = (1 << 20) + 16777216ull;

  hipMemsetAsync(counts, 0, 128, stream);
  hipMemsetAsync(out, 0, (size_t)TOKS * DDIM * 4, stream);

  cvt_x_kernel<<<TOKS * DDIM / (256 * 8), 256, 0, stream>>>(x, xb);
  router_kernel<<<TOKS / 4, 256, 0, stream>>>(x, Wg, bg, counts, tok_ids, gates);
  offsets_kernel<<<1, 64, 0, stream>>>(counts, offsets);

  if (ws_size >= base + WALL + HFULL) {
    // Mode A: all weights converted once, 1-D XCD-swizzled ffn launches
    u16* w1t = (u16*)(ws + base);
    u16* w3t = w1t + (size_t)NEXP * HDIM * DDIM;
    u16* w2t = w3t + (size_t)NEXP * HDIM * DDIM;
    u16* hb  = w2t + (size_t)NEXP * HDIM * DDIM;
    cvt_wT_kernel<<<dim3(HDIM / 64, DDIM / 64, NEXP), 256, 0, stream>>>(w1, w1t, DDIM, HDIM);
    cvt_wT_kernel<<<dim3(HDIM / 64, DDIM / 64, NEXP), 256, 0, stream>>>(w3, w3t, DDIM, HDIM);
    cvt_wT_kernel<<<dim3(DDIM / 64, HDIM / 64, NEXP), 256, 0, stream>>>(w2, w2t, HDIM, DDIM);
    ffn1_kernel<<<dim3(NEXP * 16 * 64), 256, 0, stream>>>(
        xb, w1t, w3t, tok_ids, counts, offsets, hb, 0, HDIM, -1);
    ffn2_kernel<<<dim3(NEXP * 8 * 64), 256, 0, stream>>>(
        hb, w2t, tok_ids, gates, counts, offsets, out, 0, HDIM, -1);
  } else {
    // Mode B: per-expert weight buffers + h chunking
    int hw = 128;
    const int cand[5] = {2048, 1024, 512, 256, 128};
    for (int i = 0; i < 5; ++i)
      if (base + 3 * WEXP + (size_t)TOKS * cand[i] * 2 <= ws_size) { hw = cand[i]; break; }
    u16* w1t = (u16*)(ws + base);
    u16* w3t = w1t + (size_t)HDIM * DDIM;
    u16* w2t = w3t + (size_t)HDIM * DDIM;
    u16* hb  = w2t + (size_t)HDIM * DDIM;
    for (int e = 0; e < NEXP; ++e) {
      cvt_wT_kernel<<<dim3(HDIM / 64, DDIM / 64, 1), 256, 0, stream>>>(
          w1 + (size_t)e * DDIM * HDIM, w1t, DDIM, HDIM);
      cvt_wT_kernel<<<dim3(HDIM / 64, DDIM / 64, 1), 256, 0, stream>>>(
          w3 + (size_t)e * DDIM * HDIM, w3t, DDIM, HDIM);
      cvt_wT_kernel<<<dim3(DDIM / 64, HDIM / 64, 1), 256, 0, stream>>>(
          w2 + (size_t)e * HDIM * DDIM, w2t, HDIM, DDIM);
      for (int nbase = 0; nbase < HDIM; nbase += hw) {
        ffn1_kernel<<<dim3(64, hw / 128, 1), 256, 0, stream>>>(
            xb, w1t, w3t, tok_ids, counts, offsets, hb, nbase, hw, e);
        ffn2_kernel<<<dim3(64, DDIM / 128, 1), 256, 0, stream>>>(
            hb, w2t, tok_ids, gates, counts, offsets, out, nbase, hw, e);
      }
    }
  }
}